// Round 21
// baseline (166.470 us; speedup 1.0000x reference)
//
#include <hip/hip_runtime.h>
#include <math.h>

// NoisyTopKGating via fp16x2-split MFMA — R17 structure + fused split-K reduction
// (last-arriver epilogue; reduce kernel deleted).
// gemm: BM=128 rows, K-split=2 (grid 256 = 1 block/CU), 1024 thr = 16 waves
// (4 rg x 4 cg). x staged via global_load_lds (NBUF=4 x 16KB, counted vmcnt);
// W via register parity pipeline (plain float4 loads from packed frags, dist-2).
// After partial write: __threadfence + atomicAdd(flag[rt]); the SECOND arriver
// reads both K-halves and runs softplus/noise/top-2/softmax for its 128 rows.
// Flags zeroed by split_w each launch (same-stream ordering).
// out layout (f32 flat): weights [N,2] @0, indices-as-float [N,2] @32768, clean [N,64] @65536.
// d_ws: wh (512KB) @0, wl (512KB) @512KB, partials [2][16384][128] f32 (16MB) @1MB,
//       flags (128 ints) @17MB.
// Packed W layout (f16 units): [(kc*8 + cg*2 + cf)*512 + lane*8 + j]
//   col = cg*32 + cf*16 + (lane&15),  k = kc*32 + (lane>>4)*8 + j.

constexpr int NROWS = 16384;
constexpr int DDIM  = 2048;
constexpr int EDIM  = 64;
constexpr int BM    = 128;            // rows per block
constexpr int NKS   = 32;             // k-steps of 32 per block (K-half = 1024)
constexpr int IDX_OFF   = NROWS * 2;
constexpr int CLEAN_OFF = NROWS * 4;
constexpr size_t WPACK = 262144;      // f16 elements per packed matrix (128*2048)
constexpr int XS    = 16384;          // x buffer: [128 rows][32 k] f32
constexpr int NBUF  = 4;              // 64KB dynamic LDS

typedef _Float16 f16x8 __attribute__((ext_vector_type(8)));
typedef float    f32x4 __attribute__((ext_vector_type(4)));

__device__ __forceinline__ float softplus_f(float z) {
    return fmaxf(z, 0.0f) + log1pf(expf(-fabsf(z)));
}

__device__ __forceinline__ void gload16(const void* g, void* l) {
    __builtin_amdgcn_global_load_lds(
        (const __attribute__((address_space(1))) unsigned int*)g,
        (__attribute__((address_space(3))) unsigned int*)l, 16, 0, 0);
}

// ---------- kernel 1: split + pack weights; also zero the split-K flags ----------
__global__ __launch_bounds__(256) void split_w_kernel(
    const float* __restrict__ Wg, const float* __restrict__ Wn,
    _Float16* __restrict__ wh, _Float16* __restrict__ wl,
    int* __restrict__ flags)
{
    const int t    = blockIdx.x * 256 + threadIdx.x;   // 0..32767
    if (t < 128) flags[t] = 0;                          // reset per launch/replay
    const int grp  = t >> 6;                           // kc*8 + cg*2 + cf  (0..511)
    const int lane = t & 63;
    const int kc   = grp >> 3;
    const int cg   = (grp >> 1) & 3;
    const int cf   = grp & 1;
    const int col  = cg * 32 + cf * 16 + (lane & 15);
    const int k0   = kc * 32 + (lane >> 4) * 8;
    const float* src = (col < 64) ? &Wg[(size_t)col * DDIM + k0]
                                  : &Wn[(size_t)(col - 64) * DDIM + k0];
    const float4 v0 = *reinterpret_cast<const float4*>(src);
    const float4 v1 = *reinterpret_cast<const float4*>(src + 4);
    float vv[8] = {v0.x, v0.y, v0.z, v0.w, v1.x, v1.y, v1.z, v1.w};
    union { _Float16 h[8]; uint4 u; } hh, ll;
    #pragma unroll
    for (int j = 0; j < 8; ++j) {
        hh.h[j] = (_Float16)vv[j];
        ll.h[j] = (_Float16)((vv[j] - (float)hh.h[j]) * 2048.0f);
    }
    const size_t off = (size_t)grp * 512 + lane * 8;
    *reinterpret_cast<uint4*>(&wh[off]) = hh.u;
    *reinterpret_cast<uint4*>(&wl[off]) = ll.u;
}

__device__ __forceinline__ void split8(const float4 a, const float4 b, f16x8& h, f16x8& l) {
    const float v[8] = {a.x, a.y, a.z, a.w, b.x, b.y, b.z, b.w};
    #pragma unroll
    for (int j = 0; j < 8; ++j) {
        const _Float16 hh = (_Float16)v[j];
        h[j] = hh;
        l[j] = (_Float16)((v[j] - (float)hh) * 2048.0f);
    }
}

// ---------- kernel 2: partial GEMM + fused last-arriver reduction/epilogue ----------
__global__ __launch_bounds__(1024, 4) void gemm_part_kernel(
    const float* __restrict__ x,
    const float* __restrict__ noise,
    const _Float16* __restrict__ whp,
    const _Float16* __restrict__ wlp,
    float* __restrict__ pbuf,
    int* __restrict__ flags,
    float* __restrict__ out)
{
    extern __shared__ __align__(16) unsigned char smem[];   // 64KB x staging

    const int tid  = threadIdx.x;
    const int lane = tid & 63;
    const int wid  = tid >> 6;            // 0..15
    const int rg   = wid >> 2;            // row-group 0..3 (32 rows each)
    const int cg   = wid & 3;             // col-group 0..3 (32 cols each)
    const int g    = (lane >> 4) & 3;
    const int idx  = lane & 15;
    const int kh   = blockIdx.x >> 7;     // K-half 0..1
    const int rt   = blockIdx.x & 127;    // row-tile 0..127
    const int row_base = rt * BM;

    // ---- x staging: thread owns 16B of [128 rows][128B]; source pre-swizzled ----
    const int sr  = tid >> 3;             // row 0..127
    const int sq  = tid & 7;
    const int sq2 = sq ^ (sr & 7);
    const float* xsrc = x + (size_t)(row_base + sr) * DDIM + kh * 1024 + sq2 * 4;

    // ---- W base pointers (fragment-packed; per-wave 1KB contiguous per load) ----
    const char* bh2 = (const char*)whp + (size_t)kh * 262144 + (cg * 2) * 1024 + lane * 16;
    const char* bl2 = (const char*)wlp + (size_t)kh * 262144 + (cg * 2) * 1024 + lane * 16;

    // ---- A-frag read offsets (swizzled): row = rg*32 + rf*16 + idx ----
    int aoff[2][2];
    #pragma unroll
    for (int rf = 0; rf < 2; ++rf) {
        const int row = rg * 32 + rf * 16 + idx;
        #pragma unroll
        for (int j = 0; j < 2; ++j)
            aoff[rf][j] = row * 128 + (((2 * g + j) ^ (row & 7)) << 4);
    }

    f32x4 accm[2][2], accc[2][2];
    #pragma unroll
    for (int rf = 0; rf < 2; ++rf)
        #pragma unroll
        for (int cf = 0; cf < 2; ++cf) { accm[rf][cf] = (f32x4)0.0f; accc[rf][cf] = (f32x4)0.0f; }

    auto stageX = [&](int u) {
        gload16(xsrc + u * 32, smem + (u & (NBUF - 1)) * XS + tid * 16);
    };
    auto loadW = [&](int u, float4& h0, float4& h1, float4& l0, float4& l1) {
        const char* ph = bh2 + (size_t)u * 8192;
        const char* pl = bl2 + (size_t)u * 8192;
        h0 = *reinterpret_cast<const float4*>(ph);
        h1 = *reinterpret_cast<const float4*>(ph + 1024);
        l0 = *reinterpret_cast<const float4*>(pl);
        l1 = *reinterpret_cast<const float4*>(pl + 1024);
    };

    auto compute = [&](int t, const float4& h0, const float4& h1,
                       const float4& l0, const float4& l1) {
        const int b = (t & (NBUF - 1)) * XS;
        const float4 a00 = *reinterpret_cast<const float4*>(&smem[b + aoff[0][0]]);
        const float4 a01 = *reinterpret_cast<const float4*>(&smem[b + aoff[0][1]]);
        const float4 a10 = *reinterpret_cast<const float4*>(&smem[b + aoff[1][0]]);
        const float4 a11 = *reinterpret_cast<const float4*>(&smem[b + aoff[1][1]]);
        const f16x8 Bh0 = __builtin_bit_cast(f16x8, h0);
        const f16x8 Bh1 = __builtin_bit_cast(f16x8, h1);
        const f16x8 Bl0 = __builtin_bit_cast(f16x8, l0);
        const f16x8 Bl1 = __builtin_bit_cast(f16x8, l1);

        f16x8 Ah0, Al0, Ah1, Al1;
        split8(a00, a01, Ah0, Al0);
        split8(a10, a11, Ah1, Al1);

        accm[0][0] = __builtin_amdgcn_mfma_f32_16x16x32_f16(Ah0, Bh0, accm[0][0], 0, 0, 0);
        accm[0][1] = __builtin_amdgcn_mfma_f32_16x16x32_f16(Ah0, Bh1, accm[0][1], 0, 0, 0);
        accm[1][0] = __builtin_amdgcn_mfma_f32_16x16x32_f16(Ah1, Bh0, accm[1][0], 0, 0, 0);
        accm[1][1] = __builtin_amdgcn_mfma_f32_16x16x32_f16(Ah1, Bh1, accm[1][1], 0, 0, 0);
        accc[0][0] = __builtin_amdgcn_mfma_f32_16x16x32_f16(Al0, Bh0, accc[0][0], 0, 0, 0);
        accc[0][1] = __builtin_amdgcn_mfma_f32_16x16x32_f16(Al0, Bh1, accc[0][1], 0, 0, 0);
        accc[1][0] = __builtin_amdgcn_mfma_f32_16x16x32_f16(Al1, Bh0, accc[1][0], 0, 0, 0);
        accc[1][1] = __builtin_amdgcn_mfma_f32_16x16x32_f16(Al1, Bh1, accc[1][1], 0, 0, 0);
        accc[0][0] = __builtin_amdgcn_mfma_f32_16x16x32_f16(Ah0, Bl0, accc[0][0], 0, 0, 0);
        accc[0][1] = __builtin_amdgcn_mfma_f32_16x16x32_f16(Ah0, Bl1, accc[0][1], 0, 0, 0);
        accc[1][0] = __builtin_amdgcn_mfma_f32_16x16x32_f16(Ah1, Bl0, accc[1][0], 0, 0, 0);
        accc[1][1] = __builtin_amdgcn_mfma_f32_16x16x32_f16(Ah1, Bl1, accc[1][1], 0, 0, 0);
    };

    // ---- W register slots (parity) ----
    float4 s0h0, s0h1, s0l0, s0l1, s1h0, s1h1, s1l0, s1l1;

    // ---- prologue: x0,W0,x1,W1 ----
    stageX(0); loadW(0, s0h0, s0h1, s0l0, s0l1);
    stageX(1); loadW(1, s1h0, s1h1, s1l0, s1l1);
    __builtin_amdgcn_sched_barrier(0);

    // ---- main loop: t = 0..29 in parity pairs ----
    for (int tt = 0; tt < 15; ++tt) {
        const int t0 = 2 * tt;
        stageX(t0 + 2);
        asm volatile("s_waitcnt vmcnt(6)" ::: "memory");
        __builtin_amdgcn_s_barrier();
        __builtin_amdgcn_sched_barrier(0);
        compute(t0, s0h0, s0h1, s0l0, s0l1);
        loadW(t0 + 2, s0h0, s0h1, s0l0, s0l1);
        __builtin_amdgcn_sched_barrier(0);
        stageX(t0 + 3);
        asm volatile("s_waitcnt vmcnt(6)" ::: "memory");
        __builtin_amdgcn_s_barrier();
        __builtin_amdgcn_sched_barrier(0);
        compute(t0 + 1, s1h0, s1h1, s1l0, s1l1);
        loadW(t0 + 3, s1h0, s1h1, s1l0, s1l1);
        __builtin_amdgcn_sched_barrier(0);
    }
    // ---- tail t=30 ----
    asm volatile("s_waitcnt vmcnt(5)" ::: "memory");
    __builtin_amdgcn_s_barrier();
    __builtin_amdgcn_sched_barrier(0);
    compute(30, s0h0, s0h1, s0l0, s0l1);
    // ---- tail t=31 ----
    asm volatile("s_waitcnt vmcnt(0)" ::: "memory");
    __builtin_amdgcn_s_barrier();
    __builtin_amdgcn_sched_barrier(0);
    compute(31, s1h0, s1h1, s1l0, s1l1);

    // ---- write partial logits (f32), hi+lo combined ----
    float* dst = pbuf + (size_t)kh * NROWS * 128;
    #pragma unroll
    for (int rf = 0; rf < 2; ++rf)
        #pragma unroll
        for (int cf = 0; cf < 2; ++cf) {
            const int col = cg * 32 + cf * 16 + idx;
            #pragma unroll
            for (int q = 0; q < 4; ++q) {
                const int lrow = rg * 32 + rf * 16 + g * 4 + q;
                dst[(size_t)(row_base + lrow) * 128 + col] =
                    accm[rf][cf][q] + accc[rf][cf][q] * 4.8828125e-4f;
            }
        }

    // ---- split-K handshake: last arriver does the epilogue ----
    __threadfence();                               // partials visible device-wide
    __shared__ int arrived;
    if (tid == 0) arrived = atomicAdd(&flags[rt], 1);
    __syncthreads();
    if (arrived != 1) return;                      // first arriver exits

    // ---- fused epilogue: sum halves + softplus/noise/top-2/softmax (128 rows) ----
    {
        const int row = tid >> 3;                  // 0..127
        const int j   = tid & 7;
        const int e0  = j * 8;
        const int grow = row_base + row;

        const float* p0 = pbuf + (size_t)grow * 128;
        const float* p1 = pbuf + (size_t)(NROWS + grow) * 128;

        float4 c0 = *reinterpret_cast<const float4*>(&p0[e0]);
        float4 c1 = *reinterpret_cast<const float4*>(&p0[e0 + 4]);
        float4 s0 = *reinterpret_cast<const float4*>(&p0[64 + e0]);
        float4 s1 = *reinterpret_cast<const float4*>(&p0[64 + e0 + 4]);
        const float4 d0 = *reinterpret_cast<const float4*>(&p1[e0]);
        const float4 d1 = *reinterpret_cast<const float4*>(&p1[e0 + 4]);
        const float4 t0 = *reinterpret_cast<const float4*>(&p1[64 + e0]);
        const float4 t1 = *reinterpret_cast<const float4*>(&p1[64 + e0 + 4]);
        c0.x += d0.x; c0.y += d0.y; c0.z += d0.z; c0.w += d0.w;
        c1.x += d1.x; c1.y += d1.y; c1.z += d1.z; c1.w += d1.w;
        s0.x += t0.x; s0.y += t0.y; s0.z += t0.z; s0.w += t0.w;
        s1.x += t1.x; s1.y += t1.y; s1.z += t1.z; s1.w += t1.w;

        *reinterpret_cast<float4*>(&out[CLEAN_OFF + (size_t)grow * EDIM + e0])     = c0;
        *reinterpret_cast<float4*>(&out[CLEAN_OFF + (size_t)grow * EDIM + e0 + 4]) = c1;

        const float4 z0 = *reinterpret_cast<const float4*>(&noise[(size_t)grow * EDIM + e0]);
        const float4 z1 = *reinterpret_cast<const float4*>(&noise[(size_t)grow * EDIM + e0 + 4]);

        float nv[8];
        nv[0] = fmaf(softplus_f(s0.x), z0.x, c0.x);
        nv[1] = fmaf(softplus_f(s0.y), z0.y, c0.y);
        nv[2] = fmaf(softplus_f(s0.z), z0.z, c0.z);
        nv[3] = fmaf(softplus_f(s0.w), z0.w, c0.w);
        nv[4] = fmaf(softplus_f(s1.x), z1.x, c1.x);
        nv[5] = fmaf(softplus_f(s1.y), z1.y, c1.y);
        nv[6] = fmaf(softplus_f(s1.z), z1.z, c1.z);
        nv[7] = fmaf(softplus_f(s1.w), z1.w, c1.w);

        float v0 = nv[0], v1 = -INFINITY;
        int   i0 = e0,    i1 = -1;
        #pragma unroll
        for (int m = 1; m < 8; ++m) {
            const float v = nv[m]; const int e = e0 + m;
            if (v > v0)      { v1 = v0; i1 = i0; v0 = v; i0 = e; }
            else if (v > v1) { v1 = v;  i1 = e; }
        }
        #pragma unroll
        for (int d = 1; d < 8; d <<= 1) {
            const float ov0 = __shfl_xor(v0, d); const int oi0 = __shfl_xor(i0, d);
            const float ov1 = __shfl_xor(v1, d); const int oi1 = __shfl_xor(i1, d);
            const bool aFirst = (v0 > ov0) || (v0 == ov0 && i0 < oi0);
            float n0, n1; int ni0, ni1;
            if (aFirst) {
                n0 = v0; ni0 = i0;
                const bool s = (v1 > ov0) || (v1 == ov0 && i1 < oi0);
                n1 = s ? v1 : ov0; ni1 = s ? i1 : oi0;
            } else {
                n0 = ov0; ni0 = oi0;
                const bool s = (ov1 > v0) || (ov1 == v0 && oi1 < i0);
                n1 = s ? ov1 : v0; ni1 = s ? oi1 : i0;
            }
            v0 = n0; i0 = ni0; v1 = n1; i1 = ni1;
        }
        if (j == 0) {
            const float ex = expf(v1 - v0);
            const float w0 = 1.0f / (1.0f + ex);
            const float w1 = 1.0f - w0;
            out[(size_t)grow * 2 + 0] = w0;
            out[(size_t)grow * 2 + 1] = w1;
            out[IDX_OFF + (size_t)grow * 2 + 0] = (float)i0;
            out[IDX_OFF + (size_t)grow * 2 + 1] = (float)i1;
        }
    }
}

extern "C" void kernel_launch(void* const* d_in, const int* in_sizes, int n_in,
                              void* d_out, int out_size, void* d_ws, size_t ws_size,
                              hipStream_t stream) {
    const float* x     = (const float*)d_in[0];
    const float* Wg    = (const float*)d_in[1];
    const float* Wn    = (const float*)d_in[2];
    const float* noise = (const float*)d_in[3];
    float* out = (float*)d_out;

    _Float16* wh = (_Float16*)d_ws;
    _Float16* wl = wh + WPACK;                                   // +512KB
    float* pbuf  = (float*)((char*)d_ws + (1 << 20));            // 16MB partials @1MB
    int*   flags = (int*)((char*)d_ws + (17 << 20));             // 128 ints @17MB

    split_w_kernel<<<dim3(128), dim3(256), 0, stream>>>(Wg, Wn, wh, wl, flags);
    gemm_part_kernel<<<dim3(256), dim3(1024), NBUF * XS, stream>>>(
        x, noise, wh, wl, pbuf, flags, out);
}

// Round 22
// 51.038 us; speedup vs baseline: 3.2617x; 3.2617x over previous
//
#include <hip/hip_runtime.h>
#include <math.h>

// NoisyTopKGating via fp16x2-split MFMA — reverted to the round-17 best (51.3us).
// gemm: BM=128 rows, K-split=2 (grid 256 = 1 block/CU), 1024 thr = 16 waves
// (4 rg x 4 cg, per-wave 32x32 tile -> acc = 32 VGPR). x staged via global_load_lds
// (NBUF=4 x 16KB, counted vmcnt); W via register parity pipeline (plain float4
// loads from packed frags, dist-2, sched_barrier-pinned). launch_bounds(1024,4).
// Partials f32 [2][16384][128] + reduce kernel (softplus/noise/top-2/softmax).
// Every alternative to each choice measured worse in rounds 8-21 (see session log):
// reg-staged x +16%, LDS-broadcast W +8%, fused last-arriver epilogue +115us,
// barrier-free wave-private staging +12us, BM=64 full-K +6us.
// out layout (f32 flat): weights [N,2] @0, indices-as-float [N,2] @32768, clean [N,64] @65536.
// d_ws: wh (512KB) @0, wl (512KB) @512KB, partials 16MB @1MB.
// Packed W layout (f16 units): [(kc*8 + cg*2 + cf)*512 + lane*8 + j]
//   col = cg*32 + cf*16 + (lane&15),  k = kc*32 + (lane>>4)*8 + j.

constexpr int NROWS = 16384;
constexpr int DDIM  = 2048;
constexpr int EDIM  = 64;
constexpr int BM    = 128;            // rows per block
constexpr int NKS   = 32;             // k-steps of 32 per block (K-half = 1024)
constexpr int IDX_OFF   = NROWS * 2;
constexpr int CLEAN_OFF = NROWS * 4;
constexpr size_t WPACK = 262144;      // f16 elements per packed matrix (128*2048)
constexpr int XS    = 16384;          // x buffer: [128 rows][32 k] f32
constexpr int NBUF  = 4;              // 64KB dynamic LDS

typedef _Float16 f16x8 __attribute__((ext_vector_type(8)));
typedef float    f32x4 __attribute__((ext_vector_type(4)));

__device__ __forceinline__ float softplus_f(float z) {
    return fmaxf(z, 0.0f) + log1pf(expf(-fabsf(z)));
}

__device__ __forceinline__ void gload16(const void* g, void* l) {
    __builtin_amdgcn_global_load_lds(
        (const __attribute__((address_space(1))) unsigned int*)g,
        (__attribute__((address_space(3))) unsigned int*)l, 16, 0, 0);
}

// ---------- kernel 1: split + pack weights into frag-ordered hi/lo ----------
__global__ __launch_bounds__(256) void split_w_kernel(
    const float* __restrict__ Wg, const float* __restrict__ Wn,
    _Float16* __restrict__ wh, _Float16* __restrict__ wl)
{
    const int t    = blockIdx.x * 256 + threadIdx.x;   // 0..32767
    const int grp  = t >> 6;                           // kc*8 + cg*2 + cf  (0..511)
    const int lane = t & 63;
    const int kc   = grp >> 3;
    const int cg   = (grp >> 1) & 3;
    const int cf   = grp & 1;
    const int col  = cg * 32 + cf * 16 + (lane & 15);
    const int k0   = kc * 32 + (lane >> 4) * 8;
    const float* src = (col < 64) ? &Wg[(size_t)col * DDIM + k0]
                                  : &Wn[(size_t)(col - 64) * DDIM + k0];
    const float4 v0 = *reinterpret_cast<const float4*>(src);
    const float4 v1 = *reinterpret_cast<const float4*>(src + 4);
    float vv[8] = {v0.x, v0.y, v0.z, v0.w, v1.x, v1.y, v1.z, v1.w};
    union { _Float16 h[8]; uint4 u; } hh, ll;
    #pragma unroll
    for (int j = 0; j < 8; ++j) {
        hh.h[j] = (_Float16)vv[j];
        ll.h[j] = (_Float16)((vv[j] - (float)hh.h[j]) * 2048.0f);
    }
    const size_t off = (size_t)grp * 512 + lane * 8;
    *reinterpret_cast<uint4*>(&wh[off]) = hh.u;
    *reinterpret_cast<uint4*>(&wl[off]) = ll.u;
}

__device__ __forceinline__ void split8(const float4 a, const float4 b, f16x8& h, f16x8& l) {
    const float v[8] = {a.x, a.y, a.z, a.w, b.x, b.y, b.z, b.w};
    #pragma unroll
    for (int j = 0; j < 8; ++j) {
        const _Float16 hh = (_Float16)v[j];
        h[j] = hh;
        l[j] = (_Float16)((v[j] - (float)hh) * 2048.0f);
    }
}

// ---------- kernel 2: partial GEMM (128 rows x 128 cols x K=1024, 16 waves) ----------
__global__ __launch_bounds__(1024, 4) void gemm_part_kernel(
    const float* __restrict__ x,
    const _Float16* __restrict__ whp,
    const _Float16* __restrict__ wlp,
    float* __restrict__ pbuf)
{
    extern __shared__ __align__(16) unsigned char smem[];   // 64KB x staging

    const int tid  = threadIdx.x;
    const int lane = tid & 63;
    const int wid  = tid >> 6;            // 0..15
    const int rg   = wid >> 2;            // row-group 0..3 (32 rows each)
    const int cg   = wid & 3;             // col-group 0..3 (32 cols each)
    const int g    = (lane >> 4) & 3;
    const int idx  = lane & 15;
    const int kh   = blockIdx.x >> 7;     // K-half 0..1
    const int rt   = blockIdx.x & 127;    // row-tile 0..127
    const int row_base = rt * BM;

    // ---- x staging: thread stages 16B of [128 rows][128B]; source pre-swizzled ----
    const int sr  = tid >> 3;             // row 0..127
    const int sq  = tid & 7;
    const int sq2 = sq ^ (sr & 7);
    const float* xsrc = x + (size_t)(row_base + sr) * DDIM + kh * 1024 + sq2 * 4;

    // ---- W base pointers (fragment-packed; per-wave 1KB contiguous per load) ----
    const char* bh2 = (const char*)whp + (size_t)kh * 262144 + (cg * 2) * 1024 + lane * 16;
    const char* bl2 = (const char*)wlp + (size_t)kh * 262144 + (cg * 2) * 1024 + lane * 16;

    // ---- A-frag read offsets (swizzled): row = rg*32 + rf*16 + idx ----
    int aoff[2][2];
    #pragma unroll
    for (int rf = 0; rf < 2; ++rf) {
        const int row = rg * 32 + rf * 16 + idx;
        #pragma unroll
        for (int j = 0; j < 2; ++j)
            aoff[rf][j] = row * 128 + (((2 * g + j) ^ (row & 7)) << 4);
    }

    f32x4 accm[2][2], accc[2][2];
    #pragma unroll
    for (int rf = 0; rf < 2; ++rf)
        #pragma unroll
        for (int cf = 0; cf < 2; ++cf) { accm[rf][cf] = (f32x4)0.0f; accc[rf][cf] = (f32x4)0.0f; }

    auto stageX = [&](int u) {
        gload16(xsrc + u * 32, smem + (u & (NBUF - 1)) * XS + tid * 16);
    };
    auto loadW = [&](int u, float4& h0, float4& h1, float4& l0, float4& l1) {
        const char* ph = bh2 + (size_t)u * 8192;
        const char* pl = bl2 + (size_t)u * 8192;
        h0 = *reinterpret_cast<const float4*>(ph);
        h1 = *reinterpret_cast<const float4*>(ph + 1024);
        l0 = *reinterpret_cast<const float4*>(pl);
        l1 = *reinterpret_cast<const float4*>(pl + 1024);
    };

    auto compute = [&](int t, const float4& h0, const float4& h1,
                       const float4& l0, const float4& l1) {
        const int b = (t & (NBUF - 1)) * XS;
        const float4 a00 = *reinterpret_cast<const float4*>(&smem[b + aoff[0][0]]);
        const float4 a01 = *reinterpret_cast<const float4*>(&smem[b + aoff[0][1]]);
        const float4 a10 = *reinterpret_cast<const float4*>(&smem[b + aoff[1][0]]);
        const float4 a11 = *reinterpret_cast<const float4*>(&smem[b + aoff[1][1]]);
        const f16x8 Bh0 = __builtin_bit_cast(f16x8, h0);
        const f16x8 Bh1 = __builtin_bit_cast(f16x8, h1);
        const f16x8 Bl0 = __builtin_bit_cast(f16x8, l0);
        const f16x8 Bl1 = __builtin_bit_cast(f16x8, l1);

        f16x8 Ah0, Al0, Ah1, Al1;
        split8(a00, a01, Ah0, Al0);
        split8(a10, a11, Ah1, Al1);

        accm[0][0] = __builtin_amdgcn_mfma_f32_16x16x32_f16(Ah0, Bh0, accm[0][0], 0, 0, 0);
        accm[0][1] = __builtin_amdgcn_mfma_f32_16x16x32_f16(Ah0, Bh1, accm[0][1], 0, 0, 0);
        accm[1][0] = __builtin_amdgcn_mfma_f32_16x16x32_f16(Ah1, Bh0, accm[1][0], 0, 0, 0);
        accm[1][1] = __builtin_amdgcn_mfma_f32_16x16x32_f16(Ah1, Bh1, accm[1][1], 0, 0, 0);
        accc[0][0] = __builtin_amdgcn_mfma_f32_16x16x32_f16(Al0, Bh0, accc[0][0], 0, 0, 0);
        accc[0][1] = __builtin_amdgcn_mfma_f32_16x16x32_f16(Al0, Bh1, accc[0][1], 0, 0, 0);
        accc[1][0] = __builtin_amdgcn_mfma_f32_16x16x32_f16(Al1, Bh0, accc[1][0], 0, 0, 0);
        accc[1][1] = __builtin_amdgcn_mfma_f32_16x16x32_f16(Al1, Bh1, accc[1][1], 0, 0, 0);
        accc[0][0] = __builtin_amdgcn_mfma_f32_16x16x32_f16(Ah0, Bl0, accc[0][0], 0, 0, 0);
        accc[0][1] = __builtin_amdgcn_mfma_f32_16x16x32_f16(Ah0, Bl1, accc[0][1], 0, 0, 0);
        accc[1][0] = __builtin_amdgcn_mfma_f32_16x16x32_f16(Ah1, Bl0, accc[1][0], 0, 0, 0);
        accc[1][1] = __builtin_amdgcn_mfma_f32_16x16x32_f16(Ah1, Bl1, accc[1][1], 0, 0, 0);
    };

    // ---- W register slots (parity) ----
    float4 s0h0, s0h1, s0l0, s0l1, s1h0, s1h1, s1l0, s1l1;

    // ---- prologue: x0,W0,x1,W1 ----
    stageX(0); loadW(0, s0h0, s0h1, s0l0, s0l1);
    stageX(1); loadW(1, s1h0, s1h1, s1l0, s1l1);
    __builtin_amdgcn_sched_barrier(0);

    // ---- main loop: t = 0..29 in parity pairs ----
    // Body: stageX(t+2) | vmcnt(6) drains {x(t),W(t)} | barrier | compute(t) | loadW(t+2)
    for (int tt = 0; tt < 15; ++tt) {
        const int t0 = 2 * tt;
        stageX(t0 + 2);
        asm volatile("s_waitcnt vmcnt(6)" ::: "memory");
        __builtin_amdgcn_s_barrier();
        __builtin_amdgcn_sched_barrier(0);
        compute(t0, s0h0, s0h1, s0l0, s0l1);
        loadW(t0 + 2, s0h0, s0h1, s0l0, s0l1);
        __builtin_amdgcn_sched_barrier(0);
        stageX(t0 + 3);
        asm volatile("s_waitcnt vmcnt(6)" ::: "memory");
        __builtin_amdgcn_s_barrier();
        __builtin_amdgcn_sched_barrier(0);
        compute(t0 + 1, s1h0, s1h1, s1l0, s1l1);
        loadW(t0 + 3, s1h0, s1h1, s1l0, s1l1);
        __builtin_amdgcn_sched_barrier(0);
    }
    // ---- tail t=30: newer in flight = x(31)+W(31) = 5 ----
    asm volatile("s_waitcnt vmcnt(5)" ::: "memory");
    __builtin_amdgcn_s_barrier();
    __builtin_amdgcn_sched_barrier(0);
    compute(30, s0h0, s0h1, s0l0, s0l1);
    // ---- tail t=31 ----
    asm volatile("s_waitcnt vmcnt(0)" ::: "memory");
    __builtin_amdgcn_s_barrier();
    __builtin_amdgcn_sched_barrier(0);
    compute(31, s1h0, s1h1, s1l0, s1l1);

    // ---- write partial logits (f32), hi+lo combined ----
    float* dst = pbuf + (size_t)kh * NROWS * 128;
    #pragma unroll
    for (int rf = 0; rf < 2; ++rf)
        #pragma unroll
        for (int cf = 0; cf < 2; ++cf) {
            const int col = cg * 32 + cf * 16 + idx;
            #pragma unroll
            for (int q = 0; q < 4; ++q) {
                const int lrow = rg * 32 + rf * 16 + g * 4 + q;
                dst[(size_t)(row_base + lrow) * 128 + col] =
                    accm[rf][cf][q] + accc[rf][cf][q] * 4.8828125e-4f;
            }
        }
}

// ---------- kernel 3: reduce halves + softplus/noise/top-2/softmax ----------
__global__ __launch_bounds__(256) void reduce_topk_kernel(
    const float* __restrict__ pbuf,
    const float* __restrict__ noise,
    float* __restrict__ out)
{
    const int tid = threadIdx.x;
    const int row = tid >> 3;
    const int j   = tid & 7;
    const int e0  = j * 8;
    const int grow = blockIdx.x * 32 + row;

    const float* p0 = pbuf + (size_t)grow * 128;
    const float* p1 = pbuf + (size_t)(NROWS + grow) * 128;

    float4 c0 = *reinterpret_cast<const float4*>(&p0[e0]);
    float4 c1 = *reinterpret_cast<const float4*>(&p0[e0 + 4]);
    float4 s0 = *reinterpret_cast<const float4*>(&p0[64 + e0]);
    float4 s1 = *reinterpret_cast<const float4*>(&p0[64 + e0 + 4]);
    const float4 d0 = *reinterpret_cast<const float4*>(&p1[e0]);
    const float4 d1 = *reinterpret_cast<const float4*>(&p1[e0 + 4]);
    const float4 t0 = *reinterpret_cast<const float4*>(&p1[64 + e0]);
    const float4 t1 = *reinterpret_cast<const float4*>(&p1[64 + e0 + 4]);
    c0.x += d0.x; c0.y += d0.y; c0.z += d0.z; c0.w += d0.w;
    c1.x += d1.x; c1.y += d1.y; c1.z += d1.z; c1.w += d1.w;
    s0.x += t0.x; s0.y += t0.y; s0.z += t0.z; s0.w += t0.w;
    s1.x += t1.x; s1.y += t1.y; s1.z += t1.z; s1.w += t1.w;

    *reinterpret_cast<float4*>(&out[CLEAN_OFF + (size_t)grow * EDIM + e0])     = c0;
    *reinterpret_cast<float4*>(&out[CLEAN_OFF + (size_t)grow * EDIM + e0 + 4]) = c1;

    const float4 z0 = *reinterpret_cast<const float4*>(&noise[(size_t)grow * EDIM + e0]);
    const float4 z1 = *reinterpret_cast<const float4*>(&noise[(size_t)grow * EDIM + e0 + 4]);

    float nv[8];
    nv[0] = fmaf(softplus_f(s0.x), z0.x, c0.x);
    nv[1] = fmaf(softplus_f(s0.y), z0.y, c0.y);
    nv[2] = fmaf(softplus_f(s0.z), z0.z, c0.z);
    nv[3] = fmaf(softplus_f(s0.w), z0.w, c0.w);
    nv[4] = fmaf(softplus_f(s1.x), z1.x, c1.x);
    nv[5] = fmaf(softplus_f(s1.y), z1.y, c1.y);
    nv[6] = fmaf(softplus_f(s1.z), z1.z, c1.z);
    nv[7] = fmaf(softplus_f(s1.w), z1.w, c1.w);

    float v0 = nv[0], v1 = -INFINITY;
    int   i0 = e0,    i1 = -1;
    #pragma unroll
    for (int m = 1; m < 8; ++m) {
        const float v = nv[m]; const int e = e0 + m;
        if (v > v0)      { v1 = v0; i1 = i0; v0 = v; i0 = e; }
        else if (v > v1) { v1 = v;  i1 = e; }
    }
    #pragma unroll
    for (int d = 1; d < 8; d <<= 1) {
        const float ov0 = __shfl_xor(v0, d); const int oi0 = __shfl_xor(i0, d);
        const float ov1 = __shfl_xor(v1, d); const int oi1 = __shfl_xor(i1, d);
        const bool aFirst = (v0 > ov0) || (v0 == ov0 && i0 < oi0);
        float n0, n1; int ni0, ni1;
        if (aFirst) {
            n0 = v0; ni0 = i0;
            const bool s = (v1 > ov0) || (v1 == ov0 && i1 < oi0);
            n1 = s ? v1 : ov0; ni1 = s ? i1 : oi0;
        } else {
            n0 = ov0; ni0 = oi0;
            const bool s = (ov1 > v0) || (ov1 == v0 && oi1 < i0);
            n1 = s ? ov1 : v0; ni1 = s ? oi1 : i0;
        }
        v0 = n0; i0 = ni0; v1 = n1; i1 = ni1;
    }
    if (j == 0) {
        const float ex = expf(v1 - v0);
        const float w0 = 1.0f / (1.0f + ex);
        const float w1 = 1.0f - w0;
        out[(size_t)grow * 2 + 0] = w0;
        out[(size_t)grow * 2 + 1] = w1;
        out[IDX_OFF + (size_t)grow * 2 + 0] = (float)i0;
        out[IDX_OFF + (size_t)grow * 2 + 1] = (float)i1;
    }
}

extern "C" void kernel_launch(void* const* d_in, const int* in_sizes, int n_in,
                              void* d_out, int out_size, void* d_ws, size_t ws_size,
                              hipStream_t stream) {
    const float* x     = (const float*)d_in[0];
    const float* Wg    = (const float*)d_in[1];
    const float* Wn    = (const float*)d_in[2];
    const float* noise = (const float*)d_in[3];
    float* out = (float*)d_out;

    _Float16* wh = (_Float16*)d_ws;
    _Float16* wl = wh + WPACK;                                  // +512KB
    float* pbuf  = (float*)((char*)d_ws + (1 << 20));           // 16MB partials @1MB

    split_w_kernel<<<dim3(128), dim3(256), 0, stream>>>(Wg, Wn, wh, wl);
    gemm_part_kernel<<<dim3(256), dim3(1024), NBUF * XS, stream>>>(x, wh, wl, pbuf);
    reduce_topk_kernel<<<dim3(NROWS / 32), dim3(256), 0, stream>>>(pbuf, noise, out);
}